// Round 2
// baseline (605.275 us; speedup 1.0000x reference)
//
#include <hip/hip_runtime.h>
#include <hip/hip_bf16.h>
#include <cstdint>

#define E_LOCAL 8
#define HIDDEN  2048
#define INTER   1408
#define MPE     1024      // tokens per expert (8192/8)
#define BK      64
#define LDP     72        // fallback-path padded LDS stride

typedef __attribute__((ext_vector_type(8))) __bf16 bf16x8;
typedef __attribute__((ext_vector_type(4))) float  f32x4;
typedef __attribute__((ext_vector_type(8))) unsigned short u16x8;

// round-to-nearest-even f32 -> bf16 bits (finite inputs)
__device__ __forceinline__ unsigned short f2b(float f) {
    unsigned int u = __float_as_uint(f);
    unsigned int r = (u + 0x7fffu + ((u >> 16) & 1u)) >> 16;
    return (unsigned short)r;
}

// async global->LDS, 16B per lane. LDS dest = wave-uniform base + lane*16.
__device__ __forceinline__ void async16(const unsigned short* g, unsigned short* l) {
    __builtin_amdgcn_global_load_lds(
        (const __attribute__((address_space(1))) unsigned int*)g,
        (__attribute__((address_space(3))) unsigned int*)l, 16, 0, 0);
}

// ---------------- one-time dequant+convert, all three tensors in ONE launch ----------------
// 16-elem chunks: hidden 1,048,576 | w1 2,883,584 | w2 1,441,792 (all /256 -> block-uniform segment)
#define CONV_C0 1048576u
#define CONV_C1 2883584u
#define CONV_C2 1441792u
#define CONV_BLOCKS ((CONV_C0 + CONV_C1 + CONV_C2) / 256u)   // 20992

__global__ __launch_bounds__(256) void convert_all(
        const float* __restrict__ hidden, const float* __restrict__ w1,
        const float* __restrict__ s1, const float* __restrict__ w2,
        const float* __restrict__ s2,
        unsigned short* __restrict__ bh, unsigned short* __restrict__ bw1,
        unsigned short* __restrict__ bw2)
{
    unsigned int g = blockIdx.x * 256u + threadIdx.x;
    const float* src; unsigned short* dst; size_t base; float s;
    if (g < CONV_C0) {                    // hidden [8192][2048], no scale
        unsigned int r = g >> 7, c16 = g & 127u;
        base = ((size_t)r << 11) + (size_t)c16 * 16;
        s = 1.0f; src = hidden; dst = bh;
    } else if (g < CONV_C0 + CONV_C1) {   // w1 [8][2816][2048], scale [8][22][16]
        unsigned int li = g - CONV_C0;
        unsigned int r = li >> 7, c16 = li & 127u;      // r in [0, 8*2816)
        unsigned int e = r / 2816u, n = r - e * 2816u;
        base = ((size_t)r << 11) + (size_t)c16 * 16;
        s = s1[(e * 22u + (n >> 7)) * 16u + (c16 >> 3)];
        src = w1; dst = bw1;
    } else {                              // w2 [8][2048][1408], scale [8][16][11]
        unsigned int li = g - CONV_C0 - CONV_C1;
        unsigned int r = li / 88u, c16 = li - r * 88u;  // K16 = 88
        unsigned int e = r >> 11, h = r & 2047u;
        base = (size_t)r * 1408 + (size_t)c16 * 16;
        s = s2[(e * 16u + (h >> 7)) * 11u + (c16 >> 3)];
        src = w2; dst = bw2;
    }
    float4 v0 = *(const float4*)(src + base);
    float4 v1 = *(const float4*)(src + base + 4);
    float4 v2 = *(const float4*)(src + base + 8);
    float4 v3 = *(const float4*)(src + base + 12);
    u16x8 o0, o1;
    o0[0] = f2b(v0.x * s); o0[1] = f2b(v0.y * s); o0[2] = f2b(v0.z * s); o0[3] = f2b(v0.w * s);
    o0[4] = f2b(v1.x * s); o0[5] = f2b(v1.y * s); o0[6] = f2b(v1.z * s); o0[7] = f2b(v1.w * s);
    o1[0] = f2b(v2.x * s); o1[1] = f2b(v2.y * s); o1[2] = f2b(v2.z * s); o1[3] = f2b(v2.w * s);
    o1[4] = f2b(v3.x * s); o1[5] = f2b(v3.y * s); o1[6] = f2b(v3.z * s); o1[7] = f2b(v3.w * s);
    *(u16x8*)(dst + base)     = o0;
    *(u16x8*)(dst + base + 8) = o1;
}

// ---------------- GEMM1 (bf16, BK=32 double-buffered stage-ahead pipeline) ----------------
// grid: x = my (8 => one per XCD), y = nx (11), z = e (8).
// Per iter: sync (drains PREV tile's loads, issued one compute-phase ago) -> issue next tile -> compute.
// LDS tiles [128][32] bf16, XOR swizzle: stored chunk = global chunk ^ ((row>>1)&3).
// Read-side banks: per 16-lane phase, 8 distinct 16B groups x 2 lanes (2-way = free, m136).
__global__ __launch_bounds__(256, 2) void gemm1_bf16(
        const unsigned short* __restrict__ bh,    // [8192, HIDDEN] bf16
        const unsigned short* __restrict__ bw1,   // [E, 2*INTER, HIDDEN] bf16 (dequant folded)
        unsigned short* __restrict__ down_in)     // [E, MPE, INTER] bf16
{
    __shared__ alignas(16) unsigned short sA[2][128 * 32];
    __shared__ alignas(16) unsigned short sG[2][128 * 32];
    __shared__ alignas(16) unsigned short sU[2][128 * 32];

    const int my = blockIdx.x;   // 0..7
    const int nx = blockIdx.y;   // 0..10
    const int e  = blockIdx.z;   // 0..7
    const int t  = threadIdx.x;
    const int lane = t & 63;
    const int wave = t >> 6;
    const int wm   = (wave >> 1) * 64;
    const int wn   = (wave & 1) * 64;
    const int l16  = lane & 15;
    const int quad = lane >> 4;

    const unsigned short* Abase = bh  + ((size_t)e * MPE + (size_t)my * 128) * HIDDEN;
    const unsigned short* Gbase = bw1 + ((size_t)e * (2 * INTER) + (size_t)nx * 128) * HIDDEN;
    const unsigned short* Ubase = Gbase + (size_t)INTER * HIDDEN;

    // staging: lane l writes LDS row (wave*32 + j*16 + (l>>2)), chunk (l&3), j in {0,1};
    // global source chunk = (l&3) ^ ((row>>1)&3) = (l&3) ^ ((l>>3)&3)  (j*8, w*16 are ==0 mod 4)
    const int cgo = (((lane & 3) ^ ((lane >> 3) & 3)) * 8);
    const size_t g0 = (size_t)(wave * 32 + (lane >> 2)) * HIDDEN + cgo;
    const int lo0 = wave * 1024 + lane * 8;

    // read-side: global k-chunk q of row r lives at LDS chunk q ^ ((r>>1)&3); (r>>1)&3 == (l16>>1)&3
    const int cb = ((quad ^ ((l16 >> 1) & 3)) * 8);

    f32x4 accg[4][4], accu[4][4];
    #pragma unroll
    for (int i = 0; i < 4; ++i)
        #pragma unroll
        for (int j = 0; j < 4; ++j) { accg[i][j] = {0,0,0,0}; accu[i][j] = {0,0,0,0}; }

    auto stage = [&](int buf, int kt) {
        const size_t go = g0 + (size_t)kt * 32;
        async16(Abase + go,               &sA[buf][lo0]);
        async16(Abase + go + 16 * HIDDEN, &sA[buf][lo0 + 512]);
        async16(Gbase + go,               &sG[buf][lo0]);
        async16(Gbase + go + 16 * HIDDEN, &sG[buf][lo0 + 512]);
        async16(Ubase + go,               &sU[buf][lo0]);
        async16(Ubase + go + 16 * HIDDEN, &sU[buf][lo0 + 512]);
    };

    stage(0, 0);
    #pragma unroll 2
    for (int kt = 0; kt < HIDDEN / 32; ++kt) {
        const int cur = kt & 1;
        __syncthreads();                       // drains vmcnt(0): tile kt's loads (issued last iter)
        if (kt + 1 < HIDDEN / 32) stage(cur ^ 1, kt + 1);   // in flight across the NEXT sync
        bf16x8 af[4], gf[4], uf[4];
        #pragma unroll
        for (int i = 0; i < 4; ++i) {
            af[i] = *(const bf16x8*)&sA[cur][(wm + i * 16 + l16) * 32 + cb];
            gf[i] = *(const bf16x8*)&sG[cur][(wn + i * 16 + l16) * 32 + cb];
            uf[i] = *(const bf16x8*)&sU[cur][(wn + i * 16 + l16) * 32 + cb];
        }
        __builtin_amdgcn_s_setprio(1);
        #pragma unroll
        for (int mi = 0; mi < 4; ++mi)
            #pragma unroll
            for (int ni = 0; ni < 4; ++ni) {
                accg[mi][ni] = __builtin_amdgcn_mfma_f32_16x16x32_bf16(af[mi], gf[ni], accg[mi][ni], 0, 0, 0);
                accu[mi][ni] = __builtin_amdgcn_mfma_f32_16x16x32_bf16(af[mi], uf[ni], accu[mi][ni], 0, 0, 0);
            }
        __builtin_amdgcn_s_setprio(0);
    }

    unsigned short* Obase = down_in + ((size_t)e * MPE + (size_t)my * 128) * INTER + (size_t)nx * 128;
    #pragma unroll
    for (int mi = 0; mi < 4; ++mi)
        #pragma unroll
        for (int ni = 0; ni < 4; ++ni)
            #pragma unroll
            for (int r = 0; r < 4; ++r) {
                float g = accg[mi][ni][r];
                float u = accu[mi][ni][r];
                float d = g / (1.f + __expf(-g)) * u;
                int m = wm + mi * 16 + quad * 4 + r;
                int c = wn + ni * 16 + l16;
                Obase[(size_t)m * INTER + c] = f2b(d);
            }
}

// ---------------- GEMM2 (bf16, BK=32 double-buffered stage-ahead pipeline) ----------------
// grid: x = my (8), y = nx (16), z = e (8). LDS 32 KB -> up to 4-5 blocks/CU, 1024 blocks ~ one round.
__global__ __launch_bounds__(256, 2) void gemm2_bf16(
        const unsigned short* __restrict__ down_in, // [E, MPE, INTER] bf16
        const unsigned short* __restrict__ bw2,     // [E, HIDDEN, INTER] bf16 (dequant folded)
        float* __restrict__ out)                    // [E*MPE, HIDDEN]
{
    __shared__ alignas(16) unsigned short sA[2][128 * 32];
    __shared__ alignas(16) unsigned short sW[2][128 * 32];

    const int my = blockIdx.x;   // 0..7
    const int nx = blockIdx.y;   // 0..15
    const int e  = blockIdx.z;   // 0..7
    const int t  = threadIdx.x;
    const int lane = t & 63;
    const int wave = t >> 6;
    const int wm   = (wave >> 1) * 64;
    const int wn   = (wave & 1) * 64;
    const int l16  = lane & 15;
    const int quad = lane >> 4;

    const unsigned short* Abase = down_in + ((size_t)e * MPE + (size_t)my * 128) * INTER;
    const unsigned short* Wbase = bw2 + ((size_t)e * HIDDEN + (size_t)nx * 128) * INTER;

    const int cgo = (((lane & 3) ^ ((lane >> 3) & 3)) * 8);
    const size_t g0 = (size_t)(wave * 32 + (lane >> 2)) * INTER + cgo;
    const int lo0 = wave * 1024 + lane * 8;
    const int cb  = ((quad ^ ((l16 >> 1) & 3)) * 8);

    f32x4 acc[4][4];
    #pragma unroll
    for (int i = 0; i < 4; ++i)
        #pragma unroll
        for (int j = 0; j < 4; ++j) acc[i][j] = {0,0,0,0};

    auto stage = [&](int buf, int kt) {
        const size_t go = g0 + (size_t)kt * 32;
        async16(Abase + go,              &sA[buf][lo0]);
        async16(Abase + go + 16 * INTER, &sA[buf][lo0 + 512]);
        async16(Wbase + go,              &sW[buf][lo0]);
        async16(Wbase + go + 16 * INTER, &sW[buf][lo0 + 512]);
    };

    stage(0, 0);
    #pragma unroll 2
    for (int kt = 0; kt < INTER / 32; ++kt) {
        const int cur = kt & 1;
        __syncthreads();
        if (kt + 1 < INTER / 32) stage(cur ^ 1, kt + 1);
        bf16x8 af[4], wf[4];
        #pragma unroll
        for (int i = 0; i < 4; ++i) {
            af[i] = *(const bf16x8*)&sA[cur][(wm + i * 16 + l16) * 32 + cb];
            wf[i] = *(const bf16x8*)&sW[cur][(wn + i * 16 + l16) * 32 + cb];
        }
        __builtin_amdgcn_s_setprio(1);
        #pragma unroll
        for (int mi = 0; mi < 4; ++mi)
            #pragma unroll
            for (int ni = 0; ni < 4; ++ni)
                acc[mi][ni] = __builtin_amdgcn_mfma_f32_16x16x32_bf16(af[mi], wf[ni], acc[mi][ni], 0, 0, 0);
        __builtin_amdgcn_s_setprio(0);
    }

    float* Obase = out + ((size_t)e * MPE + (size_t)my * 128) * HIDDEN + (size_t)nx * 128;
    #pragma unroll
    for (int mi = 0; mi < 4; ++mi)
        #pragma unroll
        for (int ni = 0; ni < 4; ++ni)
            #pragma unroll
            for (int r = 0; r < 4; ++r) {
                int m = wm + mi * 16 + quad * 4 + r;
                int c = wn + ni * 16 + l16;
                Obase[(size_t)m * HIDDEN + c] = acc[mi][ni][r];
            }
}

// =================== fallback path (round-1 f32 kernels, used only if ws too small) ===================
__global__ __launch_bounds__(256, 2) void gemm1_f32(
        const float* __restrict__ hidden, const float* __restrict__ w1,
        const float* __restrict__ s1, unsigned short* __restrict__ down_in)
{
    __shared__ unsigned short sA[128 * LDP];
    __shared__ unsigned short sG[128 * LDP];
    __shared__ unsigned short sU[128 * LDP];
    const int nx = blockIdx.x, my = blockIdx.y, e = blockIdx.z;
    const int t = threadIdx.x, lane = t & 63, wave = t >> 6;
    const int wm = (wave >> 1) * 64, wn = (wave & 1) * 64;
    const int l16 = lane & 15, quad = lane >> 4;
    const float* Abase = hidden + ((size_t)e * MPE + (size_t)my * 128) * HIDDEN;
    const float* Gbase = w1 + ((size_t)e * (2 * INTER) + (size_t)nx * 128) * HIDDEN;
    const float* Ubase = w1 + ((size_t)e * (2 * INTER) + INTER + (size_t)nx * 128) * HIDDEN;
    f32x4 accg[4][4], accu[4][4];
    #pragma unroll
    for (int i = 0; i < 4; ++i)
        #pragma unroll
        for (int j = 0; j < 4; ++j) { accg[i][j] = {0,0,0,0}; accu[i][j] = {0,0,0,0}; }
    for (int kt = 0; kt < HIDDEN / BK; ++kt) {
        const int k0 = kt * BK;
        const int kb = k0 >> 7;
        const float sg = s1[(e * 22 + nx) * 16 + kb];
        const float su = s1[(e * 22 + 11 + nx) * 16 + kb];
        __syncthreads();
        #pragma unroll
        for (int i = 0; i < 8; ++i) {
            int idx = i * 256 + t; int r = idx >> 4, c4 = idx & 15;
            float4 v = *(const float4*)(Abase + (size_t)r * HIDDEN + k0 + c4 * 4);
            ushort4 p = { f2b(v.x), f2b(v.y), f2b(v.z), f2b(v.w) };
            *(ushort4*)&sA[r * LDP + c4 * 4] = p;
        }
        #pragma unroll
        for (int i = 0; i < 8; ++i) {
            int idx = i * 256 + t; int r = idx >> 4, c4 = idx & 15;
            float4 v = *(const float4*)(Gbase + (size_t)r * HIDDEN + k0 + c4 * 4);
            ushort4 p = { f2b(v.x * sg), f2b(v.y * sg), f2b(v.z * sg), f2b(v.w * sg) };
            *(ushort4*)&sG[r * LDP + c4 * 4] = p;
        }
        #pragma unroll
        for (int i = 0; i < 8; ++i) {
            int idx = i * 256 + t; int r = idx >> 4, c4 = idx & 15;
            float4 v = *(const float4*)(Ubase + (size_t)r * HIDDEN + k0 + c4 * 4);
            ushort4 p = { f2b(v.x * su), f2b(v.y * su), f2b(v.z * su), f2b(v.w * su) };
            *(ushort4*)&sU[r * LDP + c4 * 4] = p;
        }
        __syncthreads();
        #pragma unroll
        for (int kk = 0; kk < BK; kk += 32) {
            bf16x8 af[4], gf[4], uf[4];
            #pragma unroll
            for (int i = 0; i < 4; ++i) {
                af[i] = *(const bf16x8*)&sA[(wm + i * 16 + l16) * LDP + kk + quad * 8];
                gf[i] = *(const bf16x8*)&sG[(wn + i * 16 + l16) * LDP + kk + quad * 8];
                uf[i] = *(const bf16x8*)&sU[(wn + i * 16 + l16) * LDP + kk + quad * 8];
            }
            #pragma unroll
            for (int mi = 0; mi < 4; ++mi)
                #pragma unroll
                for (int ni = 0; ni < 4; ++ni) {
                    accg[mi][ni] = __builtin_amdgcn_mfma_f32_16x16x32_bf16(af[mi], gf[ni], accg[mi][ni], 0, 0, 0);
                    accu[mi][ni] = __builtin_amdgcn_mfma_f32_16x16x32_bf16(af[mi], uf[ni], accu[mi][ni], 0, 0, 0);
                }
        }
    }
    unsigned short* Obase = down_in + ((size_t)e * MPE + (size_t)my * 128) * INTER + (size_t)nx * 128;
    #pragma unroll
    for (int mi = 0; mi < 4; ++mi)
        #pragma unroll
        for (int ni = 0; ni < 4; ++ni)
            #pragma unroll
            for (int r = 0; r < 4; ++r) {
                float g = accg[mi][ni][r], u = accu[mi][ni][r];
                float d = g / (1.f + __expf(-g)) * u;
                int m = wm + mi * 16 + quad * 4 + r, c = wn + ni * 16 + l16;
                Obase[(size_t)m * INTER + c] = f2b(d);
            }
}

__global__ __launch_bounds__(256, 2) void gemm2_f32(
        const unsigned short* __restrict__ down_in, const float* __restrict__ w2,
        const float* __restrict__ s2, float* __restrict__ out)
{
    __shared__ unsigned short sA[128 * LDP];
    __shared__ unsigned short sW[128 * LDP];
    const int nx = blockIdx.x, my = blockIdx.y, e = blockIdx.z;
    const int t = threadIdx.x, lane = t & 63, wave = t >> 6;
    const int wm = (wave >> 1) * 64, wn = (wave & 1) * 64;
    const int l16 = lane & 15, quad = lane >> 4;
    const unsigned short* Abase = down_in + ((size_t)e * MPE + (size_t)my * 128) * INTER;
    const float* Wbase = w2 + ((size_t)e * HIDDEN + (size_t)nx * 128) * INTER;
    f32x4 acc[4][4];
    #pragma unroll
    for (int i = 0; i < 4; ++i)
        #pragma unroll
        for (int j = 0; j < 4; ++j) acc[i][j] = {0,0,0,0};
    for (int kt = 0; kt < INTER / BK; ++kt) {
        const int k0 = kt * BK;
        const float sc = s2[(e * 16 + nx) * 11 + (k0 >> 7)];
        __syncthreads();
        #pragma unroll
        for (int i = 0; i < 4; ++i) {
            int idx = i * 256 + t; int r = idx >> 3, c8 = idx & 7;
            uint4 v = *(const uint4*)(Abase + (size_t)r * INTER + k0 + c8 * 8);
            *(uint4*)&sA[r * LDP + c8 * 8] = v;
        }
        #pragma unroll
        for (int i = 0; i < 8; ++i) {
            int idx = i * 256 + t; int r = idx >> 4, c4 = idx & 15;
            float4 v = *(const float4*)(Wbase + (size_t)r * INTER + k0 + c4 * 4);
            ushort4 p = { f2b(v.x * sc), f2b(v.y * sc), f2b(v.z * sc), f2b(v.w * sc) };
            *(ushort4*)&sW[r * LDP + c4 * 4] = p;
        }
        __syncthreads();
        #pragma unroll
        for (int kk = 0; kk < BK; kk += 32) {
            bf16x8 af[4], wf[4];
            #pragma unroll
            for (int i = 0; i < 4; ++i) {
                af[i] = *(const bf16x8*)&sA[(wm + i * 16 + l16) * LDP + kk + quad * 8];
                wf[i] = *(const bf16x8*)&sW[(wn + i * 16 + l16) * LDP + kk + quad * 8];
            }
            #pragma unroll
            for (int mi = 0; mi < 4; ++mi)
                #pragma unroll
                for (int ni = 0; ni < 4; ++ni)
                    acc[mi][ni] = __builtin_amdgcn_mfma_f32_16x16x32_bf16(af[mi], wf[ni], acc[mi][ni], 0, 0, 0);
        }
    }
    float* Obase = out + ((size_t)e * MPE + (size_t)my * 128) * HIDDEN + (size_t)nx * 128;
    #pragma unroll
    for (int mi = 0; mi < 4; ++mi)
        #pragma unroll
        for (int ni = 0; ni < 4; ++ni)
            #pragma unroll
            for (int r = 0; r < 4; ++r) {
                int m = wm + mi * 16 + quad * 4 + r, c = wn + ni * 16 + l16;
                Obase[(size_t)m * HIDDEN + c] = acc[mi][ni][r];
            }
}

extern "C" void kernel_launch(void* const* d_in, const int* in_sizes, int n_in,
                              void* d_out, int out_size, void* d_ws, size_t ws_size,
                              hipStream_t stream) {
    const float* hidden = (const float*)d_in[0];
    const float* w1 = (const float*)d_in[2];
    const float* s1 = (const float*)d_in[3];
    const float* w2 = (const float*)d_in[4];
    const float* s2 = (const float*)d_in[5];
    float* out = (float*)d_out;

    const size_t SZ_BH  = (size_t)8192 * HIDDEN * 2;                // 33.55 MB
    const size_t SZ_BW1 = (size_t)E_LOCAL * 2 * INTER * HIDDEN * 2; // 92.27 MB
    const size_t SZ_BW2 = (size_t)E_LOCAL * HIDDEN * INTER * 2;     // 46.14 MB
    const size_t SZ_DI  = (size_t)E_LOCAL * MPE * INTER * 2;        // 23.07 MB
    const size_t NEED = SZ_BH + SZ_BW1 + SZ_BW2 + SZ_DI;

    dim3 blk(256);
    if (ws_size >= NEED) {
        char* w = (char*)d_ws;
        unsigned short* bh      = (unsigned short*)w;            w += SZ_BH;
        unsigned short* bw1     = (unsigned short*)w;            w += SZ_BW1;
        unsigned short* bw2     = (unsigned short*)w;            w += SZ_BW2;
        unsigned short* down_in = (unsigned short*)w;

        convert_all<<<dim3(CONV_BLOCKS), blk, 0, stream>>>(hidden, w1, s1, w2, s2, bh, bw1, bw2);

        gemm1_bf16<<<dim3(MPE / 128, INTER / 128, E_LOCAL), blk, 0, stream>>>(bh, bw1, down_in);
        gemm2_bf16<<<dim3(MPE / 128, HIDDEN / 128, E_LOCAL), blk, 0, stream>>>(down_in, bw2, out);
    } else {
        unsigned short* down_in = (unsigned short*)d_ws;
        gemm1_f32<<<dim3(INTER / 128, MPE / 128, E_LOCAL), blk, 0, stream>>>(hidden, w1, s1, down_in);
        gemm2_f32<<<dim3(HIDDEN / 128, MPE / 128, E_LOCAL), blk, 0, stream>>>(down_in, w2, s2, out);
    }
}

// Round 3
// 576.863 us; speedup vs baseline: 1.0493x; 1.0493x over previous
//
#include <hip/hip_runtime.h>
#include <hip/hip_bf16.h>
#include <cstdint>

#define E_LOCAL 8
#define HIDDEN  2048
#define INTER   1408
#define MPE     1024      // tokens per expert (8192/8)
#define BK      64
#define LDP     72        // fallback-path padded LDS stride

typedef __attribute__((ext_vector_type(8))) __bf16 bf16x8;
typedef __attribute__((ext_vector_type(4))) float  f32x4;
typedef __attribute__((ext_vector_type(8))) unsigned short u16x8;

// round-to-nearest-even f32 -> bf16 bits (finite inputs)
__device__ __forceinline__ unsigned short f2b(float f) {
    unsigned int u = __float_as_uint(f);
    unsigned int r = (u + 0x7fffu + ((u >> 16) & 1u)) >> 16;
    return (unsigned short)r;
}

// async global->LDS, 16B per lane. LDS dest = wave-uniform base + lane*16.
__device__ __forceinline__ void async16(const unsigned short* g, unsigned short* l) {
    __builtin_amdgcn_global_load_lds(
        (const __attribute__((address_space(1))) unsigned int*)g,
        (__attribute__((address_space(3))) unsigned int*)l, 16, 0, 0);
}

// ---------------- one-time dequant+convert, fully-coalesced (16B/lane loads) ----------------
// 4-elem chunks: hidden 4,194,304 | w1 11,534,336 | w2 5,767,168  (all /1024 -> uniform per (block,j))
#define C0_4 4194304u
#define C1_4 11534336u
#define C2_4 5767168u
#define CONV_BLOCKS ((C0_4 + C1_4 + C2_4) / 1024u)   // 20992, 4 chunks/thread

__global__ __launch_bounds__(256) void convert_all(
        const float* __restrict__ hidden, const float* __restrict__ w1,
        const float* __restrict__ s1, const float* __restrict__ w2,
        const float* __restrict__ s2,
        unsigned short* __restrict__ bh, unsigned short* __restrict__ bw1,
        unsigned short* __restrict__ bw2)
{
    #pragma unroll
    for (int j = 0; j < 4; ++j) {
        unsigned int g = blockIdx.x * 1024u + j * 256u + threadIdx.x;
        const float* src; unsigned short* dst; size_t base; float s;
        if (g < C0_4) {                        // hidden [8192][2048], no scale
            base = (size_t)g * 4;
            s = 1.0f; src = hidden; dst = bh;
        } else if (g < C0_4 + C1_4) {          // w1 [8][2816][2048], scale [8][22][16]
            unsigned int li = g - C0_4;
            unsigned int r = li >> 9;          // row (512 4-chunks per 2048-row)
            unsigned int kb = (li & 511u) >> 5;
            unsigned int e = r / 2816u, n = r - e * 2816u;
            base = (size_t)li * 4;
            s = s1[(e * 22u + (n >> 7)) * 16u + kb];
            src = w1; dst = bw1;
        } else {                               // w2 [8][2048][1408], scale [8][16][11]
            unsigned int li = g - C0_4 - C1_4;
            unsigned int r = li / 352u;        // 352 4-chunks per 1408-row
            unsigned int c4 = li - r * 352u;
            unsigned int e = r >> 11, h = r & 2047u;
            base = (size_t)li * 4;
            s = s2[(e * 16u + (h >> 7)) * 11u + (c4 >> 5)];
            src = w2; dst = bw2;
        }
        float4 v = *(const float4*)(src + base);
        ushort4 o = { f2b(v.x * s), f2b(v.y * s), f2b(v.z * s), f2b(v.w * s) };
        *(ushort4*)(dst + base) = o;
    }
}

// ---------------- GEMM1: BK=32, triple-buffer, depth-2 prefetch, counted vmcnt ----------------
// grid: x = my (8, = XCD id since id%8=my), y = nx (11), z = e (8).
// Index/swizzle math identical to HW-verified round-2 kernel; only sync scheme changed:
//   per iter: s_waitcnt vmcnt(6) (tile t's 6 loads done; t+1,t+2 stay in flight) -> s_barrier
//             -> ds_read tile t -> stage(t+2) -> MFMA.  NEVER drain vmcnt(0) in main loop (T4).
// Race ledger: reads of buf[t%3] retire before a wave passes iter-t+1 barrier (MFMA forces lgkmcnt);
// stage(t+2) writes buf[(t+2)%3], distinct from {t,t+1}%3; vmcnt+barrier orders writes->reads.
#define NT1 (HIDDEN / 32)   // 64
__global__ __launch_bounds__(256, 2) void gemm1_bf16(
        const unsigned short* __restrict__ bh,    // [8192, HIDDEN] bf16
        const unsigned short* __restrict__ bw1,   // [E, 2*INTER, HIDDEN] bf16 (dequant folded)
        unsigned short* __restrict__ down_in)     // [E, MPE, INTER] bf16
{
    __shared__ alignas(16) unsigned short sS[3][3][128 * 32];   // [buf][A,G,U] 72 KB

    const int my = blockIdx.x;   // 0..7
    const int nx = blockIdx.y;   // 0..10
    const int e  = blockIdx.z;   // 0..7
    const int t  = threadIdx.x;
    const int lane = t & 63;
    const int wave = t >> 6;
    const int wm   = (wave >> 1) * 64;
    const int wn   = (wave & 1) * 64;
    const int l16  = lane & 15;
    const int quad = lane >> 4;

    const unsigned short* Abase = bh  + ((size_t)e * MPE + (size_t)my * 128) * HIDDEN;
    const unsigned short* Gbase = bw1 + ((size_t)e * (2 * INTER) + (size_t)nx * 128) * HIDDEN;
    const unsigned short* Ubase = Gbase + (size_t)INTER * HIDDEN;

    // staging (HW-verified): lane l -> LDS row wave*32+(l>>2), chunk l&3; global chunk (l&3)^((l>>3)&3)
    const int cgo = (((lane & 3) ^ ((lane >> 3) & 3)) * 8);
    const size_t g0 = (size_t)(wave * 32 + (lane >> 2)) * HIDDEN + cgo;
    const int lo0 = wave * 1024 + lane * 8;

    // read-side (HW-verified): LDS chunk quad ^ ((l16>>1)&3) -> global k-octet = quad
    const int cb = ((quad ^ ((l16 >> 1) & 3)) * 8);

    f32x4 accg[4][4], accu[4][4];
    #pragma unroll
    for (int i = 0; i < 4; ++i)
        #pragma unroll
        for (int j = 0; j < 4; ++j) { accg[i][j] = {0,0,0,0}; accu[i][j] = {0,0,0,0}; }

    auto stage = [&](int buf, int kt) {
        const size_t go = g0 + (size_t)kt * 32;
        async16(Abase + go,               &sS[buf][0][lo0]);
        async16(Abase + go + 16 * HIDDEN, &sS[buf][0][lo0 + 512]);
        async16(Gbase + go,               &sS[buf][1][lo0]);
        async16(Gbase + go + 16 * HIDDEN, &sS[buf][1][lo0 + 512]);
        async16(Ubase + go,               &sS[buf][2][lo0]);
        async16(Ubase + go + 16 * HIDDEN, &sS[buf][2][lo0 + 512]);
    };

    stage(0, 0);
    stage(1, 1);
    int buf = 0;
    for (int kt = 0; kt < NT1; ++kt) {
        if (kt == NT1 - 1) { asm volatile("s_waitcnt vmcnt(0)" ::: "memory"); }
        else               { asm volatile("s_waitcnt vmcnt(6)" ::: "memory"); }
        __builtin_amdgcn_s_barrier();
        __builtin_amdgcn_sched_barrier(0);

        const unsigned short* bA = sS[buf][0];
        const unsigned short* bG = sS[buf][1];
        const unsigned short* bU = sS[buf][2];
        bf16x8 af[4], gf[4], uf[4];
        #pragma unroll
        for (int i = 0; i < 4; ++i) {
            af[i] = *(const bf16x8*)&bA[(wm + i * 16 + l16) * 32 + cb];
            gf[i] = *(const bf16x8*)&bG[(wn + i * 16 + l16) * 32 + cb];
            uf[i] = *(const bf16x8*)&bU[(wn + i * 16 + l16) * 32 + cb];
        }
        if (kt < NT1 - 2) {
            int nb = buf + 2; if (nb >= 3) nb -= 3;
            stage(nb, kt + 2);
        }
        __builtin_amdgcn_s_setprio(1);
        #pragma unroll
        for (int mi = 0; mi < 4; ++mi)
            #pragma unroll
            for (int ni = 0; ni < 4; ++ni) {
                accg[mi][ni] = __builtin_amdgcn_mfma_f32_16x16x32_bf16(af[mi], gf[ni], accg[mi][ni], 0, 0, 0);
                accu[mi][ni] = __builtin_amdgcn_mfma_f32_16x16x32_bf16(af[mi], uf[ni], accu[mi][ni], 0, 0, 0);
            }
        __builtin_amdgcn_s_setprio(0);
        buf = (buf == 2) ? 0 : buf + 1;
    }

    unsigned short* Obase = down_in + ((size_t)e * MPE + (size_t)my * 128) * INTER + (size_t)nx * 128;
    #pragma unroll
    for (int mi = 0; mi < 4; ++mi)
        #pragma unroll
        for (int ni = 0; ni < 4; ++ni)
            #pragma unroll
            for (int r = 0; r < 4; ++r) {
                float g = accg[mi][ni][r];
                float u = accu[mi][ni][r];
                float d = g / (1.f + __expf(-g)) * u;
                int m = wm + mi * 16 + quad * 4 + r;
                int c = wn + ni * 16 + l16;
                Obase[(size_t)m * INTER + c] = f2b(d);
            }
}

// ---------------- GEMM2: BK=32, triple-buffer, depth-2 prefetch, counted vmcnt ----------------
// grid: x = my (8), y = nx (16), z = e (8). LDS 48 KB -> 3 blocks/CU by LDS.
#define NT2 (INTER / 32)    // 44
__global__ __launch_bounds__(256, 2) void gemm2_bf16(
        const unsigned short* __restrict__ down_in, // [E, MPE, INTER] bf16
        const unsigned short* __restrict__ bw2,     // [E, HIDDEN, INTER] bf16 (dequant folded)
        float* __restrict__ out)                    // [E*MPE, HIDDEN]
{
    __shared__ alignas(16) unsigned short sS[3][2][128 * 32];   // [buf][A,W] 48 KB

    const int my = blockIdx.x;   // 0..7
    const int nx = blockIdx.y;   // 0..15
    const int e  = blockIdx.z;   // 0..7
    const int t  = threadIdx.x;
    const int lane = t & 63;
    const int wave = t >> 6;
    const int wm   = (wave >> 1) * 64;
    const int wn   = (wave & 1) * 64;
    const int l16  = lane & 15;
    const int quad = lane >> 4;

    const unsigned short* Abase = down_in + ((size_t)e * MPE + (size_t)my * 128) * INTER;
    const unsigned short* Wbase = bw2 + ((size_t)e * HIDDEN + (size_t)nx * 128) * INTER;

    const int cgo = (((lane & 3) ^ ((lane >> 3) & 3)) * 8);
    const size_t g0 = (size_t)(wave * 32 + (lane >> 2)) * INTER + cgo;
    const int lo0 = wave * 1024 + lane * 8;
    const int cb  = ((quad ^ ((l16 >> 1) & 3)) * 8);

    f32x4 acc[4][4];
    #pragma unroll
    for (int i = 0; i < 4; ++i)
        #pragma unroll
        for (int j = 0; j < 4; ++j) acc[i][j] = {0,0,0,0};

    auto stage = [&](int buf, int kt) {
        const size_t go = g0 + (size_t)kt * 32;
        async16(Abase + go,              &sS[buf][0][lo0]);
        async16(Abase + go + 16 * INTER, &sS[buf][0][lo0 + 512]);
        async16(Wbase + go,              &sS[buf][1][lo0]);
        async16(Wbase + go + 16 * INTER, &sS[buf][1][lo0 + 512]);
    };

    stage(0, 0);
    stage(1, 1);
    int buf = 0;
    for (int kt = 0; kt < NT2; ++kt) {
        if (kt == NT2 - 1) { asm volatile("s_waitcnt vmcnt(0)" ::: "memory"); }
        else               { asm volatile("s_waitcnt vmcnt(4)" ::: "memory"); }
        __builtin_amdgcn_s_barrier();
        __builtin_amdgcn_sched_barrier(0);

        const unsigned short* bA = sS[buf][0];
        const unsigned short* bW = sS[buf][1];
        bf16x8 af[4], wf[4];
        #pragma unroll
        for (int i = 0; i < 4; ++i) {
            af[i] = *(const bf16x8*)&bA[(wm + i * 16 + l16) * 32 + cb];
            wf[i] = *(const bf16x8*)&bW[(wn + i * 16 + l16) * 32 + cb];
        }
        if (kt < NT2 - 2) {
            int nb = buf + 2; if (nb >= 3) nb -= 3;
            stage(nb, kt + 2);
        }
        __builtin_amdgcn_s_setprio(1);
        #pragma unroll
        for (int mi = 0; mi < 4; ++mi)
            #pragma unroll
            for (int ni = 0; ni < 4; ++ni)
                acc[mi][ni] = __builtin_amdgcn_mfma_f32_16x16x32_bf16(af[mi], wf[ni], acc[mi][ni], 0, 0, 0);
        __builtin_amdgcn_s_setprio(0);
        buf = (buf == 2) ? 0 : buf + 1;
    }

    float* Obase = out + ((size_t)e * MPE + (size_t)my * 128) * HIDDEN + (size_t)nx * 128;
    #pragma unroll
    for (int mi = 0; mi < 4; ++mi)
        #pragma unroll
        for (int ni = 0; ni < 4; ++ni)
            #pragma unroll
            for (int r = 0; r < 4; ++r) {
                int m = wm + mi * 16 + quad * 4 + r;
                int c = wn + ni * 16 + l16;
                Obase[(size_t)m * HIDDEN + c] = acc[mi][ni][r];
            }
}

// =================== fallback path (round-1 f32 kernels, used only if ws too small) ===================
__global__ __launch_bounds__(256, 2) void gemm1_f32(
        const float* __restrict__ hidden, const float* __restrict__ w1,
        const float* __restrict__ s1, unsigned short* __restrict__ down_in)
{
    __shared__ unsigned short sA[128 * LDP];
    __shared__ unsigned short sG[128 * LDP];
    __shared__ unsigned short sU[128 * LDP];
    const int nx = blockIdx.x, my = blockIdx.y, e = blockIdx.z;
    const int t = threadIdx.x, lane = t & 63, wave = t >> 6;
    const int wm = (wave >> 1) * 64, wn = (wave & 1) * 64;
    const int l16 = lane & 15, quad = lane >> 4;
    const float* Abase = hidden + ((size_t)e * MPE + (size_t)my * 128) * HIDDEN;
    const float* Gbase = w1 + ((size_t)e * (2 * INTER) + (size_t)nx * 128) * HIDDEN;
    const float* Ubase = w1 + ((size_t)e * (2 * INTER) + INTER + (size_t)nx * 128) * HIDDEN;
    f32x4 accg[4][4], accu[4][4];
    #pragma unroll
    for (int i = 0; i < 4; ++i)
        #pragma unroll
        for (int j = 0; j < 4; ++j) { accg[i][j] = {0,0,0,0}; accu[i][j] = {0,0,0,0}; }
    for (int kt = 0; kt < HIDDEN / BK; ++kt) {
        const int k0 = kt * BK;
        const int kb = k0 >> 7;
        const float sg = s1[(e * 22 + nx) * 16 + kb];
        const float su = s1[(e * 22 + 11 + nx) * 16 + kb];
        __syncthreads();
        #pragma unroll
        for (int i = 0; i < 8; ++i) {
            int idx = i * 256 + t; int r = idx >> 4, c4 = idx & 15;
            float4 v = *(const float4*)(Abase + (size_t)r * HIDDEN + k0 + c4 * 4);
            ushort4 p = { f2b(v.x), f2b(v.y), f2b(v.z), f2b(v.w) };
            *(ushort4*)&sA[r * LDP + c4 * 4] = p;
        }
        #pragma unroll
        for (int i = 0; i < 8; ++i) {
            int idx = i * 256 + t; int r = idx >> 4, c4 = idx & 15;
            float4 v = *(const float4*)(Gbase + (size_t)r * HIDDEN + k0 + c4 * 4);
            ushort4 p = { f2b(v.x * sg), f2b(v.y * sg), f2b(v.z * sg), f2b(v.w * sg) };
            *(ushort4*)&sG[r * LDP + c4 * 4] = p;
        }
        #pragma unroll
        for (int i = 0; i < 8; ++i) {
            int idx = i * 256 + t; int r = idx >> 4, c4 = idx & 15;
            float4 v = *(const float4*)(Ubase + (size_t)r * HIDDEN + k0 + c4 * 4);
            ushort4 p = { f2b(v.x * su), f2b(v.y * su), f2b(v.z * su), f2b(v.w * su) };
            *(ushort4*)&sU[r * LDP + c4 * 4] = p;
        }
        __syncthreads();
        #pragma unroll
        for (int kk = 0; kk < BK; kk += 32) {
            bf16x8 af[4], gf[4], uf[4];
            #pragma unroll
            for (int i = 0; i < 4; ++i) {
                af[i] = *(const bf16x8*)&sA[(wm + i * 16 + l16) * LDP + kk + quad * 8];
                gf[i] = *(const bf16x8*)&sG[(wn + i * 16 + l16) * LDP + kk + quad * 8];
                uf[i] = *(const bf16x8*)&sU[(wn + i * 16 + l16) * LDP + kk + quad * 8];
            }
            #pragma unroll
            for (int mi = 0; mi < 4; ++mi)
                #pragma unroll
                for (int ni = 0; ni < 4; ++ni) {
                    accg[mi][ni] = __builtin_amdgcn_mfma_f32_16x16x32_bf16(af[mi], gf[ni], accg[mi][ni], 0, 0, 0);
                    accu[mi][ni] = __builtin_amdgcn_mfma_f32_16x16x32_bf16(af[mi], uf[ni], accu[mi][ni], 0, 0, 0);
                }
        }
    }
    unsigned short* Obase = down_in + ((size_t)e * MPE + (size_t)my * 128) * INTER + (size_t)nx * 128;
    #pragma unroll
    for (int mi = 0; mi < 4; ++mi)
        #pragma unroll
        for (int ni = 0; ni < 4; ++ni)
            #pragma unroll
            for (int r = 0; r < 4; ++r) {
                float g = accg[mi][ni][r], u = accu[mi][ni][r];
                float d = g / (1.f + __expf(-g)) * u;
                int m = wm + mi * 16 + quad * 4 + r, c = wn + ni * 16 + l16;
                Obase[(size_t)m * INTER + c] = f2b(d);
            }
}

__global__ __launch_bounds__(256, 2) void gemm2_f32(
        const unsigned short* __restrict__ down_in, const float* __restrict__ w2,
        const float* __restrict__ s2, float* __restrict__ out)
{
    __shared__ unsigned short sA[128 * LDP];
    __shared__ unsigned short sW[128 * LDP];
    const int nx = blockIdx.x, my = blockIdx.y, e = blockIdx.z;
    const int t = threadIdx.x, lane = t & 63, wave = t >> 6;
    const int wm = (wave >> 1) * 64, wn = (wave & 1) * 64;
    const int l16 = lane & 15, quad = lane >> 4;
    const unsigned short* Abase = down_in + ((size_t)e * MPE + (size_t)my * 128) * INTER;
    const float* Wbase = w2 + ((size_t)e * HIDDEN + (size_t)nx * 128) * INTER;
    f32x4 acc[4][4];
    #pragma unroll
    for (int i = 0; i < 4; ++i)
        #pragma unroll
        for (int j = 0; j < 4; ++j) acc[i][j] = {0,0,0,0};
    for (int kt = 0; kt < INTER / BK; ++kt) {
        const int k0 = kt * BK;
        const float sc = s2[(e * 16 + nx) * 11 + (k0 >> 7)];
        __syncthreads();
        #pragma unroll
        for (int i = 0; i < 4; ++i) {
            int idx = i * 256 + t; int r = idx >> 3, c8 = idx & 7;
            uint4 v = *(const uint4*)(Abase + (size_t)r * INTER + k0 + c8 * 8);
            *(uint4*)&sA[r * LDP + c8 * 8] = v;
        }
        #pragma unroll
        for (int i = 0; i < 8; ++i) {
            int idx = i * 256 + t; int r = idx >> 4, c4 = idx & 15;
            float4 v = *(const float4*)(Wbase + (size_t)r * INTER + k0 + c4 * 4);
            ushort4 p = { f2b(v.x * sc), f2b(v.y * sc), f2b(v.z * sc), f2b(v.w * sc) };
            *(ushort4*)&sW[r * LDP + c4 * 4] = p;
        }
        __syncthreads();
        #pragma unroll
        for (int kk = 0; kk < BK; kk += 32) {
            bf16x8 af[4], wf[4];
            #pragma unroll
            for (int i = 0; i < 4; ++i) {
                af[i] = *(const bf16x8*)&sA[(wm + i * 16 + l16) * LDP + kk + quad * 8];
                wf[i] = *(const bf16x8*)&sW[(wn + i * 16 + l16) * LDP + kk + quad * 8];
            }
            #pragma unroll
            for (int mi = 0; mi < 4; ++mi)
                #pragma unroll
                for (int ni = 0; ni < 4; ++ni)
                    acc[mi][ni] = __builtin_amdgcn_mfma_f32_16x16x32_bf16(af[mi], wf[ni], acc[mi][ni], 0, 0, 0);
        }
    }
    float* Obase = out + ((size_t)e * MPE + (size_t)my * 128) * HIDDEN + (size_t)nx * 128;
    #pragma unroll
    for (int mi = 0; mi < 4; ++mi)
        #pragma unroll
        for (int ni = 0; ni < 4; ++ni)
            #pragma unroll
            for (int r = 0; r < 4; ++r) {
                int m = wm + mi * 16 + quad * 4 + r, c = wn + ni * 16 + l16;
                Obase[(size_t)m * HIDDEN + c] = acc[mi][ni][r];
            }
}

extern "C" void kernel_launch(void* const* d_in, const int* in_sizes, int n_in,
                              void* d_out, int out_size, void* d_ws, size_t ws_size,
                              hipStream_t stream) {
    const float* hidden = (const float*)d_in[0];
    const float* w1 = (const float*)d_in[2];
    const float* s1 = (const float*)d_in[3];
    const float* w2 = (const float*)d_in[4];
    const float* s2 = (const float*)d_in[5];
    float* out = (float*)d_out;

    const size_t SZ_BH  = (size_t)8192 * HIDDEN * 2;                // 33.55 MB
    const size_t SZ_BW1 = (size_t)E_LOCAL * 2 * INTER * HIDDEN * 2; // 92.27 MB
    const size_t SZ_BW2 = (size_t)E_LOCAL * HIDDEN * INTER * 2;     // 46.14 MB
    const size_t SZ_DI  = (size_t)E_LOCAL * MPE * INTER * 2;        // 23.07 MB
    const size_t NEED = SZ_BH + SZ_BW1 + SZ_BW2 + SZ_DI;

    dim3 blk(256);
    if (ws_size >= NEED) {
        char* w = (char*)d_ws;
        unsigned short* bh      = (unsigned short*)w;            w += SZ_BH;
        unsigned short* bw1     = (unsigned short*)w;            w += SZ_BW1;
        unsigned short* bw2     = (unsigned short*)w;            w += SZ_BW2;
        unsigned short* down_in = (unsigned short*)w;

        convert_all<<<dim3(CONV_BLOCKS), blk, 0, stream>>>(hidden, w1, s1, w2, s2, bh, bw1, bw2);

        gemm1_bf16<<<dim3(MPE / 128, INTER / 128, E_LOCAL), blk, 0, stream>>>(bh, bw1, down_in);
        gemm2_bf16<<<dim3(MPE / 128, HIDDEN / 128, E_LOCAL), blk, 0, stream>>>(down_in, bw2, out);
    } else {
        unsigned short* down_in = (unsigned short*)d_ws;
        gemm1_f32<<<dim3(INTER / 128, MPE / 128, E_LOCAL), blk, 0, stream>>>(hidden, w1, s1, down_in);
        gemm2_f32<<<dim3(HIDDEN / 128, MPE / 128, E_LOCAL), blk, 0, stream>>>(down_in, w2, s2, out);
    }
}